// Round 9
// baseline (62.265 us; speedup 1.0000x reference)
//
#include <hip/hip_runtime.h>
#include <stdint.h>

typedef __bf16 bf16x8 __attribute__((ext_vector_type(8)));
typedef float  f32x4  __attribute__((ext_vector_type(4)));

constexpr int NB = 32, TT = 2048, JJ = 512, DD = 256;
constexpr int BM = 128, BN = 64, BK = 32;   // block tile; 8 k-steps

// LDS (16 KB + 384 B):
//   sA  [0,     8192)  bf16[128][32]: row 64 B = 4 x16B slots, slot s of row r at s^(r&3)
//   sB  [8192, 12288)  bf16[ 64][32]: same swizzle
//   w_s [12288,15360)  768 f32 (wc|wq|wm)
//   c_s [15360,15872)  128 f32;  q_s [15872,16128) 64 f32
__global__ __launch_bounds__(256, 4)
void fused_kernel(const float* __restrict__ ctx, const float* __restrict__ que,
                  const float* __restrict__ wvec, float* __restrict__ out)
{
    __shared__ __align__(1024) unsigned char lds[16384];
    float* w_s = (float*)(lds + 12288);
    float* c_s = (float*)(lds + 15360);
    float* q_s = (float*)(lds + 15872);

    const int tid = threadIdx.x;
    const int l   = tid & 63;
    const int wid = tid >> 6;

    // XCD swizzle: 4096 blocks -> 512 consecutive ids per XCD (4 whole batches)
    const int pb = blockIdx.x;
    const int id = (pb & 7) * 512 + (pb >> 3);
    const int n0 = (id & 7) * BN;
    const int m0 = ((id >> 3) & 15) * BM;
    const int bI = id >> 7;

    if (tid < 192) *(f32x4*)(w_s + tid * 4) = *(const f32x4*)(wvec + tid * 4);

    // staging geometry: A row per 2 threads (16 f32 each), B row per 4 threads (8 f32)
    const int rowA = tid >> 1, hcA = tid & 1;      // half-chunk: 16 f32
    const int rowB = tid >> 2, cB  = tid & 3;      // chunk: 8 f32

    const float* srcA = ctx + ((size_t)bI * TT + m0 + rowA) * DD + hcA * 16;
    const float* srcB = que + ((size_t)bI * JJ + n0 + rowB) * DD + cB * 8;

    f32x4 a[4], b[2];
    auto issue = [&](int ks) {
        const float* pa = srcA + ks * BK;
        a[0] = ((const f32x4*)pa)[0];  a[1] = ((const f32x4*)pa)[1];
        a[2] = ((const f32x4*)pa)[2];  a[3] = ((const f32x4*)pa)[3];
        const float* pq = srcB + ks * BK;
        b[0] = ((const f32x4*)pq)[0];  b[1] = ((const f32x4*)pq)[1];
    };
    issue(0);

    // swizzled LDS write addresses (lane-constant)
    unsigned char* wrA0 = lds +        rowA * 64 + (((hcA * 2)     ^ (rowA & 3)) << 4);
    unsigned char* wrA1 = lds +        rowA * 64 + (((hcA * 2 + 1) ^ (rowA & 3)) << 4);
    unsigned char* wrB  = lds + 8192 + rowB * 64 + ((cB            ^ (rowB & 3)) << 4);

    f32x4 acc[4][2];
    #pragma unroll
    for (int m = 0; m < 4; ++m) { acc[m][0] = f32x4{0,0,0,0}; acc[m][1] = f32x4{0,0,0,0}; }

    const int wm_0 = (wid >> 1) * 64;    // wave tile: 64 t-rows x 32 j-cols
    const int wn_0 = (wid & 1) * 32;
    const int lr = l & 15, hi = l >> 4;
    const int fsw = (lr & 3);            // fragment-read swizzle key

    float cacc = 0.f, qacc = 0.f;

    asm volatile("s_waitcnt lgkmcnt(0)" ::: "memory");   // w_s writes retired

    #pragma unroll
    for (int k = 0; k < 8; ++k) {
        __builtin_amdgcn_s_barrier();    // all frag reads of step k-1 retired

        const f32x4 wc0 = *(f32x4*)(w_s + k * BK + hcA * 16);
        const f32x4 wc1 = *(f32x4*)(w_s + k * BK + hcA * 16 + 4);
        const f32x4 wc2 = *(f32x4*)(w_s + k * BK + hcA * 16 + 8);
        const f32x4 wc3 = *(f32x4*)(w_s + k * BK + hcA * 16 + 12);
        const f32x4 wq0 = *(f32x4*)(w_s + 256 + k * BK + cB * 8);
        const f32x4 wq1 = *(f32x4*)(w_s + 256 + k * BK + cB * 8 + 4);
        const f32x4 wm0 = *(f32x4*)(w_s + 512 + k * BK + cB * 8);
        const f32x4 wm1 = *(f32x4*)(w_s + 512 + k * BK + cB * 8 + 4);

        bf16x8 pa0, pa1, pbv;
        float cp = 0.f, qp = 0.f;
        #pragma unroll
        for (int j = 0; j < 4; ++j) {
            pa0[j]     = (__bf16)a[0][j];           pa0[4 + j] = (__bf16)a[1][j];
            pa1[j]     = (__bf16)a[2][j];           pa1[4 + j] = (__bf16)a[3][j];
            pbv[j]     = (__bf16)(b[0][j] * wm0[j]); pbv[4 + j] = (__bf16)(b[1][j] * wm1[j]);
            cp += a[0][j]*wc0[j] + a[1][j]*wc1[j] + a[2][j]*wc2[j] + a[3][j]*wc3[j];
            qp += b[0][j]*wq0[j] + b[1][j]*wq1[j];
        }
        cacc += cp;  qacc += qp;
        *(bf16x8*)wrA0 = pa0;
        *(bf16x8*)wrA1 = pa1;
        *(bf16x8*)wrB  = pbv;

        if (k < 7) issue(k + 1);         // VMEM flight hides under frags+MFMA+barrier

        asm volatile("s_waitcnt lgkmcnt(0)" ::: "memory");   // ds_writes retired
        __builtin_amdgcn_sched_barrier(0);
        __builtin_amdgcn_s_barrier();    // tile k visible to all waves

        bf16x8 af[4], bfr[2];
        #pragma unroll
        for (int m = 0; m < 4; ++m) {
            const int r = wm_0 + m * 16 + lr;
            af[m] = *(const bf16x8*)(lds + r * 64 + ((hi ^ fsw) << 4));
        }
        #pragma unroll
        for (int n = 0; n < 2; ++n) {
            const int r = wn_0 + n * 16 + lr;
            bfr[n] = *(const bf16x8*)(lds + 8192 + r * 64 + ((hi ^ fsw) << 4));
        }

        // swapped operands: D row-axis = j (que), col-axis = t (ctx)
        __builtin_amdgcn_s_setprio(1);
        #pragma unroll
        for (int m = 0; m < 4; ++m)
            #pragma unroll
            for (int n = 0; n < 2; ++n)
                acc[m][n] = __builtin_amdgcn_mfma_f32_16x16x32_bf16(bfr[n], af[m],
                                                                    acc[m][n], 0, 0, 0);
        __builtin_amdgcn_s_setprio(0);
    }

    // term reduction: A rows owned by thread pairs (t^1), B rows by quads
    {
        float c = cacc;  c += __shfl_xor(c, 1);
        float q = qacc;  q += __shfl_xor(q, 1);  q += __shfl_xor(q, 2);
        if ((tid & 1) == 0) c_s[rowA] = c;
        if ((tid & 3) == 0) q_s[rowB] = q;
    }
    __syncthreads();

    // epilogue: out[t = wm_0+m*16+lr][j = wn_0+n*16+hi*4+q], f32x4 along j
    const int jb = wn_0 + hi * 4;
    #pragma unroll
    for (int m = 0; m < 4; ++m) {
        const int rowL = wm_0 + m * 16 + lr;
        const float cv = c_s[rowL];
        float* rowp = out + ((size_t)bI * TT + m0 + rowL) * JJ + n0;
        #pragma unroll
        for (int n = 0; n < 2; ++n) {
            const int colL = jb + n * 16;
            const f32x4 qv = *(const f32x4*)(q_s + colL);
            const f32x4 v = acc[m][n];
            f32x4 w = {v[0] + cv + qv[0], v[1] + cv + qv[1],
                       v[2] + cv + qv[2], v[3] + cv + qv[3]};
            *(f32x4*)(rowp + colL) = w;
        }
    }
}

extern "C" void kernel_launch(void* const* d_in, const int* in_sizes, int n_in,
                              void* d_out, int out_size, void* d_ws, size_t ws_size,
                              hipStream_t stream) {
    (void)in_sizes; (void)n_in; (void)d_ws; (void)ws_size; (void)out_size;
    const float* ctx = (const float*)d_in[0];
    const float* que = (const float*)d_in[1];
    const float* wv  = (const float*)d_in[2];
    float* out = (float*)d_out;

    fused_kernel<<<dim3(4096), dim3(256), 0, stream>>>(ctx, que, wv, out);
}